// Round 4
// baseline (95.320 us; speedup 1.0000x reference)
//
#include <hip/hip_runtime.h>

// Problem: N=30, K=100, ALPHA=0.5, B=1048576
#define NROWS    1048576
#define TILE     32                         // rows per tile
#define NBLOCKS  2048
#define NTHREADS 256
#define TILES_PER_BLOCK 16                  // 32768 tiles / 2048 blocks

// Per-tile global byte sizes (contiguous rows)
#define DP_TILE_B (TILE * 224)              // 7168 = 7 x 1KB
#define S_TILE_B  (TILE * 124)              // 3968 = 3 x 1KB + 896B tail
#define BX_TILE_B (TILE * 8)                // 256  = 1 x 256B

// LDS layout inside one buffer (all 16B-aligned)
#define LDS_DP 0
#define LDS_S1 7168
#define LDS_S2 11136
#define LDS_BX 15104
#define BUF_B  15360                        // 15 KB per buffer, x2 buffers
// total static LDS = 2*15360 + 2048 (sm) = 32768 -> 5 blocks/CU exactly

// Async global->LDS DMA. LDS dest = wave-uniform base (+ lane*width implicit).
#define GLDS16(g, l) __builtin_amdgcn_global_load_lds(                         \
    (const __attribute__((address_space(1))) void*)(g),                        \
    (__attribute__((address_space(3))) void*)(l), 16, 0, 0)
#define GLDS4(g, l) __builtin_amdgcn_global_load_lds(                          \
    (const __attribute__((address_space(1))) void*)(g),                        \
    (__attribute__((address_space(3))) void*)(l), 4, 0, 0)

// Staging split: wv0 -> 4 ops, wv1 -> 4 ops, wv2 -> 7 ops, wv3 -> 7 ops.
// S tail (3968B = 3x1KB + 896B): 3 GLDS16 + GLDS4 at 3072/3328/3584/3712;
// the last overlaps the previous by 128B (same bytes, benign).
__device__ __forceinline__ void stage_tile(unsigned char* buf,
    const char* dpg, const char* s1g, const char* s2g, const char* bxg,
    int wv, int lane)
{
    if (wv == 0) {
        #pragma unroll
        for (int c = 0; c < 4; ++c)
            GLDS16(dpg + c * 1024 + lane * 16, buf + LDS_DP + c * 1024);
    } else if (wv == 1) {
        #pragma unroll
        for (int c = 4; c < 7; ++c)
            GLDS16(dpg + c * 1024 + lane * 16, buf + LDS_DP + c * 1024);
        GLDS4(bxg + lane * 4, buf + LDS_BX);
    } else if (wv == 2) {
        #pragma unroll
        for (int c = 0; c < 3; ++c)
            GLDS16(s1g + c * 1024 + lane * 16, buf + LDS_S1 + c * 1024);
        GLDS4(s1g + 3072 + lane * 4, buf + LDS_S1 + 3072);
        GLDS4(s1g + 3328 + lane * 4, buf + LDS_S1 + 3328);
        GLDS4(s1g + 3584 + lane * 4, buf + LDS_S1 + 3584);
        GLDS4(s1g + 3712 + lane * 4, buf + LDS_S1 + 3712);
    } else {
        #pragma unroll
        for (int c = 0; c < 3; ++c)
            GLDS16(s2g + c * 1024 + lane * 16, buf + LDS_S2 + c * 1024);
        GLDS4(s2g + 3072 + lane * 4, buf + LDS_S2 + 3072);
        GLDS4(s2g + 3328 + lane * 4, buf + LDS_S2 + 3328);
        GLDS4(s2g + 3584 + lane * 4, buf + LDS_S2 + 3584);
        GLDS4(s2g + 3712 + lane * 4, buf + LDS_S2 + 3712);
    }
}

// Counted wait: allow this wave's OWN prefetch (issued for next tile) to stay
// in flight; drain everything older. vmcnt is per-wave, so counts differ by wave.
__device__ __forceinline__ void wait_own_prefetch(int wv)
{
    if (wv < 2) asm volatile("s_waitcnt vmcnt(4)" ::: "memory");
    else        asm volatile("s_waitcnt vmcnt(7)" ::: "memory");
}

// 128 threads compute: 4 lanes per row, 7 pairs each, shuffle-combine.
__device__ __forceinline__ void compute_tile(const unsigned char* buf,
    int row, int seg, float w, double& acc)
{
    const float*  s1row = (const float*)(buf + LDS_S1 + row * 124);
    const float*  s2row = (const float*)(buf + LDS_S2 + row * 124);
    const float2* dprow = (const float2*)(buf + LDS_DP + row * 224);
    const float2  b2    = *(const float2*)(buf + LDS_BX + row * 8);

    const int sb = 7 * seg;
    float s1v[9], s2v[9];
    #pragma unroll
    for (int i = 0; i < 9; ++i) { s1v[i] = s1row[sb + i]; s2v[i] = s2row[sb + i]; }

    float sum = 0.0f;
    #pragma unroll
    for (int u = 0; u < 7; ++u) {
        const float2 d = dprow[sb + u];     // (d1[p], d2[p]), p = sb+u
        sum += d.x * (s1v[u + 2] - s1v[u + 1]) + d.y * (s2v[u + 2] - s2v[u + 1]);
    }
    const float t0 = b2.x * (s1v[1] - s1v[0]) + b2.y * (s2v[1] - s2v[0]);
    sum += (seg == 0) ? t0 : 0.0f;

    sum += __shfl_xor(sum, 1);
    sum += __shfl_xor(sum, 2);

    const float liab = fmaxf(s1row[30] - 100.0f, 0.0f);
    const float loss = w + fmaxf(liab - sum - w, 0.0f) * 2.0f;   // /(1-ALPHA)
    if (seg == 0) acc += (double)loss;
}

__global__ __launch_bounds__(NTHREADS) void loss_pipe_kernel(
    const float* __restrict__ dp, const float* __restrict__ bx,
    const float* __restrict__ S1, const float* __restrict__ S2,
    const float* __restrict__ wp, double* __restrict__ partial)
{
    __shared__ __align__(16) unsigned char lds[2 * BUF_B];
    __shared__ double sm[NTHREADS];

    const int tid  = threadIdx.x;
    const int lane = tid & 63;
    const int wv   = tid >> 6;
    const int row  = (tid & 127) >> 2;      // 0..31 (tid<128 computes)
    const int seg  = tid & 3;               // 0..3
    const float w  = *wp;

    const long tile0 = (long)blockIdx.x * TILES_PER_BLOCK;
    double acc = 0.0;

    // prologue: stage tile 0 into buf0
    stage_tile(lds,
               (const char*)dp + tile0 * DP_TILE_B,
               (const char*)S1 + tile0 * S_TILE_B,
               (const char*)S2 + tile0 * S_TILE_B,
               (const char*)bx + tile0 * BX_TILE_B, wv, lane);

    for (int t = 0; t < TILES_PER_BLOCK - 1; ++t) {
        const long nt = tile0 + t + 1;
        stage_tile(lds + ((t + 1) & 1) * BUF_B,     // prefetch next tile
                   (const char*)dp + nt * DP_TILE_B,
                   (const char*)S1 + nt * S_TILE_B,
                   (const char*)S2 + nt * S_TILE_B,
                   (const char*)bx + nt * BX_TILE_B, wv, lane);
        wait_own_prefetch(wv);              // tile t ready; prefetch in flight
        __builtin_amdgcn_s_barrier();
        if (tid < 128) compute_tile(lds + (t & 1) * BUF_B, row, seg, w, acc);
        __builtin_amdgcn_s_barrier();       // done reading before overwrite
    }
    // epilogue: last tile
    asm volatile("s_waitcnt vmcnt(0)" ::: "memory");
    __builtin_amdgcn_s_barrier();
    if (tid < 128)
        compute_tile(lds + ((TILES_PER_BLOCK - 1) & 1) * BUF_B, row, seg, w, acc);

    // deterministic block reduction (double)
    sm[tid] = acc;
    __syncthreads();
    #pragma unroll
    for (int s = NTHREADS / 2; s > 0; s >>= 1) {
        if (tid < s) sm[tid] += sm[tid + s];
        __syncthreads();
    }
    if (tid == 0) partial[blockIdx.x] = sm[0];
}

__global__ __launch_bounds__(NTHREADS) void loss_final_kernel(
    const double* __restrict__ partial, float* __restrict__ out)
{
    double acc = 0.0;
    for (int i = threadIdx.x; i < NBLOCKS; i += NTHREADS) acc += partial[i];
    __shared__ double sm[NTHREADS];
    sm[threadIdx.x] = acc;
    __syncthreads();
    #pragma unroll
    for (int s = NTHREADS / 2; s > 0; s >>= 1) {
        if (threadIdx.x < s) sm[threadIdx.x] += sm[threadIdx.x + s];
        __syncthreads();
    }
    if (threadIdx.x == 0) out[0] = (float)(sm[0] / (double)NROWS);
}

extern "C" void kernel_launch(void* const* d_in, const int* in_sizes, int n_in,
                              void* d_out, int out_size, void* d_ws, size_t ws_size,
                              hipStream_t stream)
{
    const float* dp = (const float*)d_in[0];   // delta_pred [B,56]
    const float* bx = (const float*)d_in[1];   // batch_x    [B,2]
    const float* S1 = (const float*)d_in[2];   // S1         [B,31]
    const float* S2 = (const float*)d_in[3];   // S2         [B,31]
    const float* w  = (const float*)d_in[4];   // scalar

    double* partial = (double*)d_ws;           // NBLOCKS doubles (16 KiB)
    float* out = (float*)d_out;

    loss_pipe_kernel<<<NBLOCKS, NTHREADS, 0, stream>>>(dp, bx, S1, S2, w, partial);
    loss_final_kernel<<<1, NTHREADS, 0, stream>>>(partial, out);
}